// Round 12
// baseline (37.421 us; speedup 1.0000x reference)
//
#include <hip/hip_runtime.h>

// LabelSmoothing: weighted soft-target CE, C=3, prefix-valid mask, per-sample
// mean, batch sum. Two-kernel structure (round-9 config: NSPLIT=16, NTH=256 —
// best at 24.3 us). Per chunk: row-0 probe (empty -> exit) else ONE
// unconditional bulk round; masked compute is free (zero-label rows
// contribute 0 loss / 0 count).
// Round-12: nontemporal loads via clang native ext_vector_type (the builtin
// rejects HIP_vector_type classes) -- read-once streams skip L2/L3 allocation.

#define NB      512
#define NS      16384
#define NSPLIT  16
#define RPB     (NS / NSPLIT)   // 1024 rows per chunk
#define NTH     256
#define NBLK    (NB * NSPLIT)   // 8192 blocks

typedef int   v4i __attribute__((ext_vector_type(4)));
typedef float v4f __attribute__((ext_vector_type(4)));

__device__ __forceinline__ float row_loss(float xa, float xb, float xc,
                                          int la, int lb, int lc) {
    const float w0 = 1.23954983922f, w1 = 5.3172413793f, w2 = 192.75f;
    float m   = fmaxf(fmaxf(xa, xb), xc);
    float lse = m + __logf(__expf(xa - m) + __expf(xb - m) + __expf(xc - m));
    return w0 * (float)la * (lse - xa)
         + w1 * (float)lb * (lse - xb)
         + w2 * (float)lc * (lse - xc);
}

__global__ __launch_bounds__(NTH) void ls_partial(
    const float* __restrict__ x, const int* __restrict__ lab,
    float* __restrict__ psum, int* __restrict__ pcnt)
{
    const int blk = blockIdx.x;           // 0 .. NBLK-1
    const int b   = blk & (NB - 1);       // sp-major: consecutive blocks ->
    const int sp  = blk >> 9;             // consecutive samples, same split
    const long long base = ((long long)b * NS + (long long)sp * RPB) * 3;
    const int*   lr = lab + base;
    const float* xr = x   + base;

    // single classification probe: row 0 (uniform loads, broadcast)
    int f0 = __builtin_nontemporal_load(lr + 0);
    int f1 = __builtin_nontemporal_load(lr + 1);
    int f2 = __builtin_nontemporal_load(lr + 2);
    if ((f0 | f1 | f2) == 0) {            // whole chunk past the prefix
        if (threadIdx.x == 0) { psum[blk] = 0.0f; pcnt[blk] = 0; }
        return;
    }

    // ---- one unconditional bulk round: 6 x 16B nontemporal loads ----
    const v4i* lp0 = (const v4i*)lr + (size_t)threadIdx.x * 3;
    const v4f* xp0 = (const v4f*)xr + (size_t)threadIdx.x * 3;

    v4i a0 = __builtin_nontemporal_load(lp0 + 0);
    v4i a1 = __builtin_nontemporal_load(lp0 + 1);
    v4i a2 = __builtin_nontemporal_load(lp0 + 2);
    v4f u0 = __builtin_nontemporal_load(xp0 + 0);
    v4f u1 = __builtin_nontemporal_load(xp0 + 1);
    v4f u2 = __builtin_nontemporal_load(xp0 + 2);

    // zero-label rows contribute 0 loss and 0 count -- no masking needed
    float sumA = 0.0f, sumB = 0.0f;
    int   cnt  = 0;
    sumA += row_loss(u0.x, u0.y, u0.z, a0.x, a0.y, a0.z);
    cnt  += ((a0.x | a0.y | a0.z) != 0);
    sumB += row_loss(u0.w, u1.x, u1.y, a0.w, a1.x, a1.y);
    cnt  += ((a0.w | a1.x | a1.y) != 0);
    sumA += row_loss(u1.z, u1.w, u2.x, a1.z, a1.w, a2.x);
    cnt  += ((a1.z | a1.w | a2.x) != 0);
    sumB += row_loss(u2.y, u2.z, u2.w, a2.y, a2.z, a2.w);
    cnt  += ((a2.y | a2.z | a2.w) != 0);

    // wave (64-lane) + block reduction of sum and cnt
    float sum = sumA + sumB;
#pragma unroll
    for (int off = 32; off > 0; off >>= 1) {
        sum += __shfl_down(sum, off);
        cnt += __shfl_down(cnt, off);
    }
    __shared__ float ssum[NTH / 64];
    __shared__ int   scnt[NTH / 64];
    const int lane = threadIdx.x & 63;
    const int wid  = threadIdx.x >> 6;
    if (lane == 0) { ssum[wid] = sum; scnt[wid] = cnt; }
    __syncthreads();
    if (threadIdx.x == 0) {
        float ts = 0.0f; int tc = 0;
#pragma unroll
        for (int i = 0; i < NTH / 64; ++i) { ts += ssum[i]; tc += scnt[i]; }
        psum[blk] = ts;
        pcnt[blk] = tc;
    }
}

__global__ __launch_bounds__(NB) void ls_final(
    const float* __restrict__ psum, const int* __restrict__ pcnt,
    float* __restrict__ out)
{
    const int b = threadIdx.x;            // one thread per sample
    float s = 0.0f; int c = 0;
#pragma unroll
    for (int i = 0; i < NSPLIT; ++i) {
        s += psum[i * NB + b];            // sp-major layout
        c += pcnt[i * NB + b];
    }
    float per = s / (float)c;             // c >= 1 (lengths are 1..S)

#pragma unroll
    for (int off = 32; off > 0; off >>= 1) per += __shfl_down(per, off);
    __shared__ float sh[NB / 64];
    const int lane = threadIdx.x & 63;
    const int wid  = threadIdx.x >> 6;
    if (lane == 0) sh[wid] = per;
    __syncthreads();
    if (threadIdx.x == 0) {
        float t = 0.0f;
#pragma unroll
        for (int i = 0; i < NB / 64; ++i) t += sh[i];
        out[0] = t;
    }
}

extern "C" void kernel_launch(void* const* d_in, const int* in_sizes, int n_in,
                              void* d_out, int out_size, void* d_ws, size_t ws_size,
                              hipStream_t stream)
{
    const float* x   = (const float*)d_in[0];
    const int*   lab = (const int*)d_in[1];

    float* psum = (float*)d_ws;
    int*   pcnt = (int*)((char*)d_ws + (size_t)NBLK * sizeof(float));

    ls_partial<<<NBLK, NTH, 0, stream>>>(x, lab, psum, pcnt);
    ls_final<<<1, NB, 0, stream>>>(psum, pcnt, (float*)d_out);
}

// Round 13
// 24.621 us; speedup vs baseline: 1.5199x; 1.5199x over previous
//
#include <hip/hip_runtime.h>

// LabelSmoothing: weighted soft-target CE, C=3, prefix-valid mask, per-sample
// mean, batch sum. Two-kernel structure (round-9 config: NSPLIT=16, NTH=256,
// best measured 24.3 us). Per chunk: row-0 probe (empty -> exit) else ONE
// unconditional bulk round; masked compute is free (zero-label rows
// contribute 0 loss / 0 count).
// Round-13: revert round-12's nontemporal loads (24.3 -> 37.4 us regression:
// nt bypasses L2 sector reuse between probe and bulk + MALL burst smoothing).
// Micro: (1) sp==0 chunks are always nonempty (lengths >= 1) -> skip probe;
// (2) pack (psum,pcnt) into float2 -> one 8B store, contiguous final read.

#define NB      512
#define NS      16384
#define NSPLIT  16
#define RPB     (NS / NSPLIT)   // 1024 rows per chunk
#define NTH     256
#define NBLK    (NB * NSPLIT)   // 8192 blocks

__device__ __forceinline__ float row_loss(float xa, float xb, float xc,
                                          int la, int lb, int lc) {
    const float w0 = 1.23954983922f, w1 = 5.3172413793f, w2 = 192.75f;
    float m   = fmaxf(fmaxf(xa, xb), xc);
    float lse = m + __logf(__expf(xa - m) + __expf(xb - m) + __expf(xc - m));
    return w0 * (float)la * (lse - xa)
         + w1 * (float)lb * (lse - xb)
         + w2 * (float)lc * (lse - xc);
}

__global__ __launch_bounds__(NTH) void ls_partial(
    const float* __restrict__ x, const int* __restrict__ lab,
    float2* __restrict__ part)
{
    const int blk = blockIdx.x;           // 0 .. NBLK-1
    const int b   = blk & (NB - 1);       // sp-major: consecutive blocks ->
    const int sp  = blk >> 9;             // consecutive samples, same split
    const long long base = ((long long)b * NS + (long long)sp * RPB) * 3;
    const int*   lr = lab + base;
    const float* xr = x   + base;

    // classification probe: row 0. sp==0 is always nonempty (lengths >= 1).
    if (sp != 0) {
        int f0 = lr[0], f1 = lr[1], f2 = lr[2];
        if ((f0 | f1 | f2) == 0) {        // whole chunk past the prefix
            if (threadIdx.x == 0) part[blk] = make_float2(0.0f, 0.0f);
            return;
        }
    }

    // ---- one unconditional bulk round: 6 x 16B hoisted loads ----
    const int4*   lp0 = (const int4*)lr + (size_t)threadIdx.x * 3;
    const float4* xp0 = (const float4*)xr + (size_t)threadIdx.x * 3;

    int4   a0 = lp0[0], a1 = lp0[1], a2 = lp0[2];
    float4 u0 = xp0[0], u1 = xp0[1], u2 = xp0[2];

    // zero-label rows contribute 0 loss and 0 count -- no masking needed
    float sumA = 0.0f, sumB = 0.0f;
    int   cnt  = 0;
    sumA += row_loss(u0.x, u0.y, u0.z, a0.x, a0.y, a0.z);
    cnt  += ((a0.x | a0.y | a0.z) != 0);
    sumB += row_loss(u0.w, u1.x, u1.y, a0.w, a1.x, a1.y);
    cnt  += ((a0.w | a1.x | a1.y) != 0);
    sumA += row_loss(u1.z, u1.w, u2.x, a1.z, a1.w, a2.x);
    cnt  += ((a1.z | a1.w | a2.x) != 0);
    sumB += row_loss(u2.y, u2.z, u2.w, a2.y, a2.z, a2.w);
    cnt  += ((a2.y | a2.z | a2.w) != 0);

    // wave (64-lane) + block reduction of sum and cnt
    float sum = sumA + sumB;
    float fcnt = (float)cnt;
#pragma unroll
    for (int off = 32; off > 0; off >>= 1) {
        sum  += __shfl_down(sum, off);
        fcnt += __shfl_down(fcnt, off);
    }
    __shared__ float ssum[NTH / 64];
    __shared__ float scnt[NTH / 64];
    const int lane = threadIdx.x & 63;
    const int wid  = threadIdx.x >> 6;
    if (lane == 0) { ssum[wid] = sum; scnt[wid] = fcnt; }
    __syncthreads();
    if (threadIdx.x == 0) {
        float ts = 0.0f, tc = 0.0f;
#pragma unroll
        for (int i = 0; i < NTH / 64; ++i) { ts += ssum[i]; tc += scnt[i]; }
        part[blk] = make_float2(ts, tc);
    }
}

__global__ __launch_bounds__(NB) void ls_final(
    const float2* __restrict__ part, float* __restrict__ out)
{
    const int b = threadIdx.x;            // one thread per sample
    float s = 0.0f, c = 0.0f;
#pragma unroll
    for (int i = 0; i < NSPLIT; ++i) {
        float2 p = part[i * NB + b];      // sp-major layout
        s += p.x;
        c += p.y;
    }
    float per = s / c;                    // c >= 1 (lengths are 1..S)

#pragma unroll
    for (int off = 32; off > 0; off >>= 1) per += __shfl_down(per, off);
    __shared__ float sh[NB / 64];
    const int lane = threadIdx.x & 63;
    const int wid  = threadIdx.x >> 6;
    if (lane == 0) sh[wid] = per;
    __syncthreads();
    if (threadIdx.x == 0) {
        float t = 0.0f;
#pragma unroll
        for (int i = 0; i < NB / 64; ++i) t += sh[i];
        out[0] = t;
    }
}

extern "C" void kernel_launch(void* const* d_in, const int* in_sizes, int n_in,
                              void* d_out, int out_size, void* d_ws, size_t ws_size,
                              hipStream_t stream)
{
    const float* x   = (const float*)d_in[0];
    const int*   lab = (const int*)d_in[1];

    float2* part = (float2*)d_ws;

    ls_partial<<<NBLK, NTH, 0, stream>>>(x, lab, part);
    ls_final<<<1, NB, 0, stream>>>(part, (float*)d_out);
}